// Round 3
// baseline (500.249 us; speedup 1.0000x reference)
//
#include <hip/hip_runtime.h>
#include <hip/hip_bf16.h>

// 6-level 2D DB4 wavelet (forward -> soft threshold -> inverse), N=4096 fp32.
// R3: 3 kernels total.
//   K1 fwd0: level-0 forward (4096 blocks).
//   K2 small_levels: persistent 256-block kernel, fwd levels 1-5 (+final thr)
//      and inv levels 5-1, with 9 software grid barriers (agent-scope atomics).
//      256 blocks @ 40KB LDS are trivially co-resident (capacity 4/CU x 256 CU).
//   K3 inv0: level-0 inverse (1024 blocks).
//
// d_out layout: [0 .. 16777216) reconstruction, [16777216 .. 33554432) flat coeffs.
// Flat level l: rows of [hh|hl|lh], row stride 3*sh; final thr(approx) 64x64 tail.
//
// ws (floats): A1 0..4194304, A2 ..5242880, A3 ..5505024, A4 ..5570560,
// A5 ..5586944, I5 ..5603328, I4 ..5668864, I3 ..5931008, I2 ..6979584,
// I1 ..11173888, barrier counter @ 11173888. All regions write-once-then-read
// within a call => no stale-L2 address-reuse hazard across barrier stages.

#define NBLK_SMALL 256

__device__ __forceinline__ float thrf(float t, float alpha, float bp, float bm) {
    float s1 = 1.0f / (1.0f + __expf(-alpha * (t - bp)));
    float s2 = 1.0f / (1.0f + __expf( alpha * (t + bm)));
    return t * (s1 + s2);
}

__device__ __forceinline__ void load_filt(const float* __restrict__ filt,
                                          float (&h)[8], float (&w)[8]) {
#pragma unroll
    for (int k = 0; k < 8; ++k) h[k] = filt[k];
#pragma unroll
    for (int k = 0; k < 8; ++k) w[k] = (k & 1) ? -h[7 - k] : h[7 - k];
}

// Forward level over tiles [tstart, ntiles) step tstep. X (s x s) ->
// thresholded hh|hl|lh into flat (stride 3*sh), raw ll into All (if non-null),
// thresholded ll into thrA (if non-null). 32x32 output tile.
// smem: xs 72*73 | Ds 72*33 | As 72*33  (10008 floats)
__device__ void fwd_tiles(const float* __restrict__ X, int s, int sh,
                          float* __restrict__ flat, float* __restrict__ All,
                          float* __restrict__ thrA,
                          const float* __restrict__ frow,
                          const float* __restrict__ fcol,
                          float alpha, float bp, float bm,
                          float* smem, int tstart, int tstep) {
    float hr[8], wr[8], hc[8], wc[8];
    load_filt(frow, hr, wr);
    load_filt(fcol, hc, wc);
    float* xs = smem;          // [72][73]
    float* Ds = smem + 5256;   // [72][33]
    float* As = smem + 7632;   // [72][33]
    const int tid = threadIdx.x;
    const int sm = s - 1;
    const int ntx = sh >> 5;
    const int ntiles = ntx * ntx;
    const int shft = __builtin_ctz(ntx);
    for (int t = tstart; t < ntiles; t += tstep) {
        const int i0 = (t >> shft) * 32, j0 = (t & (ntx - 1)) * 32;
        for (int idx = tid; idx < 72 * 72; idx += 256) {
            int rr = idx / 72, cc = idx - rr * 72;
            xs[rr * 73 + cc] =
                X[(size_t)((2 * i0 - 7 + rr) & sm) * s + ((2 * j0 - 7 + cc) & sm)];
        }
        __syncthreads();
        for (int idx = tid; idx < 72 * 32; idx += 256) {
            int rr = idx >> 5, j = idx & 31;
            float d = 0.f, a = 0.f;
#pragma unroll
            for (int k = 0; k < 8; ++k) {
                float v = xs[rr * 73 + 2 * j + 7 - k];
                d += wr[k] * v;
                a += hr[k] * v;
            }
            Ds[rr * 33 + j] = d;
            As[rr * 33 + j] = a;
        }
        __syncthreads();
        for (int idx = tid; idx < 32 * 32; idx += 256) {
            int i = idx >> 5, j = idx & 31;
            float hh = 0.f, hl = 0.f, lh = 0.f, ll = 0.f;
#pragma unroll
            for (int k = 0; k < 8; ++k) {
                float dv = Ds[(2 * i + 7 - k) * 33 + j];
                float av = As[(2 * i + 7 - k) * 33 + j];
                hh += wc[k] * dv;
                hl += hc[k] * dv;
                lh += wc[k] * av;
                ll += hc[k] * av;
            }
            size_t ro = (size_t)(i0 + i) * (3 * sh) + (j0 + j);
            flat[ro]          = thrf(hh, alpha, bp, bm);
            flat[ro + sh]     = thrf(hl, alpha, bp, bm);
            flat[ro + 2 * sh] = thrf(lh, alpha, bp, bm);
            size_t ao = (size_t)(i0 + i) * sh + (j0 + j);
            if (All)  All[ao]  = ll;
            if (thrA) thrA[ao] = thrf(ll, alpha, bp, bm);
        }
        __syncthreads();
    }
}

// Inverse level over tiles. flatl rows [hh|hl|lh] stride 3*sc, a stride sc ->
// out 64x64 full-res tile (stride ostride).
// smem: hh 36*37 | hl | lh | as (4*1332) | Hs 64*37 | Ls 64*37 (10064 floats)
__device__ void inv_tiles(const float* __restrict__ flatl,
                          const float* __restrict__ a, int sc,
                          float* __restrict__ outp, int ostride,
                          const float* __restrict__ fcol,
                          const float* __restrict__ frow,
                          float* smem, int tstart, int tstep) {
    float hr[8], wr[8], hc[8], wc[8];
    load_filt(frow, hr, wr);
    load_filt(fcol, hc, wc);
    float* hhs = smem;            // [36][37]
    float* hls = smem + 1332;
    float* lhs = smem + 2664;
    float* as_ = smem + 3996;
    float* Hs  = smem + 5328;     // [64][37]
    float* Ls  = smem + 7696;
    const int tid = threadIdx.x;
    const int mm = sc - 1;
    const int r = 2 * sc;
    const int ntx = r >> 6;
    const int ntiles = ntx * ntx;
    const int shft = __builtin_ctz(ntx);
    const int ds = 3 * sc;
    for (int t = tstart; t < ntiles; t += tstep) {
        const int i0 = (t >> shft) * 64, m0 = (t & (ntx - 1)) * 64;
        const int r0 = i0 >> 1, c0 = m0 >> 1;
        for (int idx = tid; idx < 36 * 36; idx += 256) {
            int rr = idx / 36, cc = idx - rr * 36;
            int gr = (r0 + rr) & mm, gc = (c0 + cc) & mm;
            size_t fo = (size_t)gr * ds + gc;
            hhs[rr * 37 + cc] = flatl[fo];
            hls[rr * 37 + cc] = flatl[fo + sc];
            lhs[rr * 37 + cc] = flatl[fo + 2 * sc];
            as_[rr * 37 + cc] = a[(size_t)gr * sc + gc];
        }
        __syncthreads();
        for (int idx = tid; idx < 64 * 36; idx += 256) {
            int n = idx / 36, jj = idx - n * 36;
            int nh = n >> 1;
            float Hv = 0.f, Lv = 0.f;
            if ((n & 1) == 0) {
#pragma unroll
                for (int tt = 0; tt < 4; ++tt) {
                    int lr = (nh + tt) * 37 + jj;
                    Hv += wc[2 * tt] * hhs[lr] + hc[2 * tt] * hls[lr];
                    Lv += wc[2 * tt] * lhs[lr] + hc[2 * tt] * as_[lr];
                }
            } else {
#pragma unroll
                for (int tt = 0; tt < 4; ++tt) {
                    int lr = (nh + tt + 1) * 37 + jj;
                    Hv += wc[2 * tt + 1] * hhs[lr] + hc[2 * tt + 1] * hls[lr];
                    Lv += wc[2 * tt + 1] * lhs[lr] + hc[2 * tt + 1] * as_[lr];
                }
            }
            Hs[n * 37 + jj] = Hv;
            Ls[n * 37 + jj] = Lv;
        }
        __syncthreads();
        for (int idx = tid; idx < 64 * 64; idx += 256) {
            int i = idx >> 6, m = idx & 63;
            int mh = m >> 1;
            float acc = 0.f;
            if ((m & 1) == 0) {
#pragma unroll
                for (int tt = 0; tt < 4; ++tt) {
                    int lc = mh + tt;
                    acc += wr[2 * tt] * Hs[i * 37 + lc] + hr[2 * tt] * Ls[i * 37 + lc];
                }
            } else {
#pragma unroll
                for (int tt = 0; tt < 4; ++tt) {
                    int lc = mh + tt + 1;
                    acc += wr[2 * tt + 1] * Hs[i * 37 + lc] + hr[2 * tt + 1] * Ls[i * 37 + lc];
                }
            }
            outp[(size_t)(i0 + i) * ostride + (m0 + m)] = acc;
        }
        __syncthreads();
    }
}

__device__ __forceinline__ void grid_barrier(unsigned* c, unsigned target) {
    __syncthreads();
    if (threadIdx.x == 0) {
        __hip_atomic_fetch_add(c, 1u, __ATOMIC_RELEASE, __HIP_MEMORY_SCOPE_AGENT);
        while (__hip_atomic_load(c, __ATOMIC_ACQUIRE, __HIP_MEMORY_SCOPE_AGENT) < target) {
            __builtin_amdgcn_s_sleep(1);
        }
    }
    __syncthreads();
}

__global__ __launch_bounds__(256) void fwd0_kernel(
    const float* __restrict__ X, float* __restrict__ flat, float* __restrict__ A1,
    const float* __restrict__ scal, const float* __restrict__ ap,
    const float* __restrict__ bpp, const float* __restrict__ bmp) {
    __shared__ float smem[10064];
    fwd_tiles(X, 4096, 2048, flat, A1, nullptr, scal, scal + 8,
              *ap, *bpp, *bmp, smem, blockIdx.x, gridDim.x);
}

__global__ __launch_bounds__(256) void small_levels_kernel(
    float* __restrict__ ws, float* __restrict__ out,
    const float* __restrict__ scal, const float* __restrict__ ap,
    const float* __restrict__ bpp, const float* __restrict__ bmp,
    unsigned* __restrict__ counter) {
    __shared__ float smem[10064];
    const float alpha = *ap, bp = *bpp, bm = *bmp;
    float* flat = out + 16777216;
    const size_t Aoff[6]    = {0, 0, 4194304, 5242880, 5505024, 5570560};
    const size_t Ioff[6]    = {0, 6979584, 5931008, 5668864, 5603328, 5586944};
    const size_t flatOff[6] = {0, 12582912, 15728640, 16515072, 16711680, 16760832};
    const size_t finalOff = 16773120;
    unsigned phase = 0;
    // forward levels 1..5 (level 5 also writes thresholded final approx)
    for (int lev = 1; lev <= 5; ++lev) {
        int s = 4096 >> lev, sh = s >> 1;
        fwd_tiles(ws + Aoff[lev], s, sh, flat + flatOff[lev],
                  (lev < 5) ? (ws + Aoff[lev + 1]) : nullptr,
                  (lev == 5) ? (flat + finalOff) : nullptr,
                  scal + lev * 8, scal + (lev + 1) * 8,
                  alpha, bp, bm, smem, blockIdx.x, gridDim.x);
        grid_barrier(counter, (++phase) * NBLK_SMALL);
    }
    // inverse levels 5..1
    const float* a_in = flat + finalOff;
    for (int lev = 5; lev >= 1; --lev) {
        int sc = 4096 >> (lev + 1);
        float* outp = ws + Ioff[lev];
        inv_tiles(flat + flatOff[lev], a_in, sc, outp, 2 * sc,
                  scal + (lev + 1) * 8, scal + lev * 8,
                  smem, blockIdx.x, gridDim.x);
        if (lev > 1) grid_barrier(counter, (++phase) * NBLK_SMALL);
        a_in = outp;
    }
}

__global__ __launch_bounds__(256) void inv0_kernel(
    const float* __restrict__ flatl, const float* __restrict__ a,
    float* __restrict__ recon, const float* __restrict__ scal) {
    __shared__ float smem[10064];
    inv_tiles(flatl, a, 2048, recon, 4096, scal + 8, scal,
              smem, blockIdx.x, gridDim.x);
}

extern "C" void kernel_launch(void* const* d_in, const int* in_sizes, int n_in,
                              void* d_out, int out_size, void* d_ws, size_t ws_size,
                              hipStream_t stream) {
    const float* x    = (const float*)d_in[0];
    const float* scal = (const float*)d_in[1];  // 12 x 8
    const float* ap   = (const float*)d_in[2];
    const float* bp   = (const float*)d_in[3];
    const float* bm   = (const float*)d_in[4];
    float* out = (float*)d_out;
    float* ws  = (float*)d_ws;

    float* flat = out + 16777216;
    unsigned* counter = (unsigned*)(ws + 11173888);

    // zero the barrier counter (memset node is graph-capture legal)
    hipMemsetAsync(counter, 0, sizeof(unsigned), stream);

    // K1: forward level 0
    fwd0_kernel<<<dim3(64 * 64), dim3(256), 0, stream>>>(
        x, flat, ws /* A1 at offset 0 */, scal, ap, bp, bm);

    // K2: everything small (fwd 1-5 + final thr + inv 5-1), 9 grid barriers
    small_levels_kernel<<<dim3(NBLK_SMALL), dim3(256), 0, stream>>>(
        ws, out, scal, ap, bp, bm, counter);

    // K3: inverse level 0 (reads flat lev0 + I1, writes recon)
    inv0_kernel<<<dim3(32 * 32), dim3(256), 0, stream>>>(
        flat, ws + 6979584, out, scal);
}